// Round 15
// baseline (17.328 us; speedup 1.0000x reference)
//
#include <hip/hip_runtime.h>

// SVR: out[i] = sum_j exp(-|f_i-f_j|^2/50)*alpha[j] + bias.  N=4096, D=64.
// Round 15 = R14 (15.84us) + per-output overhead halving:
//  - WPT=8 i-tiles per wave (was 4): A-frag + aj VMEM issue per output /2.
//    grid (8,32) = 256 blocks = 1 block/CU (R12 proved TLP-insensitivity).
//  - prep writes eip[row] = exp2(-si2) directly; main loads it (no sq2, no
//    prologue exp); ajp[row] = alpha[row]*eip[row] comes free in prep.
// exp identity: exp(-(si+sj-2dot)/50) = exp2(K1*dot)*eip_i*eip_j; data scaled
// by sqrt(K1) so chained MFMA emits K1*dot. Raw v_exp_f32 via builtin.
//
// Frag map (16x16x32 bf16): lane l of tile t, half h: row=16*t+(l&15),
// k=32*h+(l>>4)*8..+7 -> chunk (t*2+h)*64+l.  A/B share lane->k map.
// C/D: col=lane&15 (i), row=(lane>>4)*4+reg (j)  [verified m89; R4-R14 passed]

#define NN 4096
#define DD 64
#define NPY 32                 // j-chunks; 8 j-tiles (128 j-rows... 256 j-rows) each
#define NT (NN / 16)           // 256 row-tiles
#define WPT 8                  // i-tiles per wave

typedef __attribute__((ext_vector_type(8))) short bf16x8;
typedef __attribute__((ext_vector_type(8))) unsigned short u16x8;
typedef __attribute__((ext_vector_type(4))) float f32x4;

#define C2 0.028853901f        // log2(e)/50
#define SQK 0.2402244f         // sqrt(2*log2(e)/50)

static __device__ __forceinline__ float fexp2(float x) {   // raw v_exp_f32 (2^x)
#if __has_builtin(__builtin_amdgcn_exp2f)
    return __builtin_amdgcn_exp2f(x);
#else
    float r;
    asm("v_exp_f32 %0, %1" : "=v"(r) : "v"(x));
    return r;
#endif
}

static __device__ __forceinline__ unsigned short f2bf(float f) {
    unsigned int x = __float_as_uint(f);
    x += 0x7fffu + ((x >> 16) & 1u);          // RNE
    return (unsigned short)(x >> 16);
}

// ---------- prep: retile+convert (scaled), eip, ajp, out=bias ----------
__global__ __launch_bounds__(256) void svr_prep(const float* __restrict__ F,
                                                const float* __restrict__ alpha,
                                                const float* __restrict__ bias,
                                                u16x8* __restrict__ Ft,
                                                float* __restrict__ eip,
                                                float* __restrict__ ajp,
                                                float* __restrict__ out) {
    __shared__ float part[256];
    const int tid = threadIdx.x;
    const int g = blockIdx.x * 256 + tid;           // 0..32767
    const int l = g & 63;
    const int h = (g >> 6) & 1;
    const int t = g >> 7;
    const int row = t * 16 + (l & 15);
    const int k0  = h * 32 + (l >> 4) * 8;

    const float4* src = reinterpret_cast<const float4*>(F + (size_t)row * DD + k0);
    const float4 v0 = src[0];
    const float4 v1 = src[1];
    u16x8 u;                                        // scaled by sqrt(K1)
    u[0] = f2bf(v0.x * SQK); u[1] = f2bf(v0.y * SQK);
    u[2] = f2bf(v0.z * SQK); u[3] = f2bf(v0.w * SQK);
    u[4] = f2bf(v1.x * SQK); u[5] = f2bf(v1.y * SQK);
    u[6] = f2bf(v1.z * SQK); u[7] = f2bf(v1.w * SQK);
    Ft[g] = u;

    float p = v0.x * v0.x;                          // unscaled norms
    p = fmaf(v0.y, v0.y, p); p = fmaf(v0.z, v0.z, p); p = fmaf(v0.w, v0.w, p);
    p = fmaf(v1.x, v1.x, p); p = fmaf(v1.y, v1.y, p); p = fmaf(v1.z, v1.z, p);
    p = fmaf(v1.w, v1.w, p);
    part[tid] = p;
    __syncthreads();
    if ((tid & 112) == 0) {    // one thread per row: tid in {0..15, 128..143}
        float s = part[tid]      + part[tid + 16] + part[tid + 32] + part[tid + 48]
                + part[tid + 64] + part[tid + 80] + part[tid + 96] + part[tid + 112];
        const float e = fexp2(-s * C2);             // exp2(-|f|^2*log2e/50)
        eip[row] = e;
        ajp[row] = alpha[row] * e;                  // alpha_j * exp2(-sj2)
    }
    if (g < NN) out[g] = bias[0];                   // re-init every call
}

// ---------- main: 8 i-tiles/wave, chained MFMA, raw exp2, atomics ----------
__global__ __launch_bounds__(256) void svr_mfma8(const bf16x8* __restrict__ Ft,
                                                 const float* __restrict__ ajp,
                                                 const float* __restrict__ eip,
                                                 float* __restrict__ out) {
    const int lane = threadIdx.x & 63;
    const int wave = threadIdx.x >> 6;
    const int ig   = blockIdx.x * 4 + wave;          // i-group 0..31 (128 rows)
    const int it0  = ig * WPT;
    const int iBase = it0 * 16;
    const int p    = blockIdx.y;                     // 0..31
    const int jt0  = p * (NT / NPY);                 // 8 j-tiles
    const int kg   = lane >> 4;
    const int c    = lane & 15;

    // B-frags for 8 i-tiles (64 VGPR, resident) + i-side exp scales
    bf16x8 b0[WPT], b1[WPT];
    float  e[WPT];
#pragma unroll
    for (int q = 0; q < WPT; ++q) {
        b0[q] = Ft[(it0 + q) * 128 + lane];          // 1KB coalesced
        b1[q] = Ft[(it0 + q) * 128 + 64 + lane];
        e[q]  = eip[iBase + q * 16 + c];
    }

    const float4* alv = reinterpret_cast<const float4*>(ajp);

    f32x4 acc[WPT];
#pragma unroll
    for (int q = 0; q < WPT; ++q) acc[q] = (f32x4){0.f, 0.f, 0.f, 0.f};

#pragma unroll
    for (int k = 0; k < NT / NPY; ++k) {
        const int jt = jt0 + k;
        const bf16x8 a0 = Ft[jt * 128 + lane];       // 1KB coalesced
        const bf16x8 a1 = Ft[jt * 128 + 64 + lane];
        const float4 aj = alv[jt * 4 + kg];
#pragma unroll
        for (int q = 0; q < WPT; ++q) {
            f32x4 d = {0.f, 0.f, 0.f, 0.f};
            d = __builtin_amdgcn_mfma_f32_16x16x32_bf16(a0, b0[q], d, 0, 0, 0);
            d = __builtin_amdgcn_mfma_f32_16x16x32_bf16(a1, b1[q], d, 0, 0, 0);
            acc[q].x = fmaf(fexp2(d[0]), aj.x, acc[q].x);
            acc[q].y = fmaf(fexp2(d[1]), aj.y, acc[q].y);
            acc[q].z = fmaf(fexp2(d[2]), aj.z, acc[q].z);
            acc[q].w = fmaf(fexp2(d[3]), aj.w, acc[q].w);
        }
    }

#pragma unroll
    for (int q = 0; q < WPT; ++q) {
        float s = (acc[q].x + acc[q].y) + (acc[q].z + acc[q].w);
        s += __shfl_xor(s, 16);
        s += __shfl_xor(s, 32);
        if (lane < 16) atomicAdd(&out[iBase + q * 16 + lane], s * e[q]);
    }
}

// ---------------- launch ----------------
extern "C" void kernel_launch(void* const* d_in, const int* in_sizes, int n_in,
                              void* d_out, int out_size, void* d_ws, size_t ws_size,
                              hipStream_t stream) {
    const float* F     = (const float*)d_in[0];
    const float* alpha = (const float*)d_in[1];
    const float* bias  = (const float*)d_in[2];
    float* out = (float*)d_out;

    u16x8* Ft  = (u16x8*)d_ws;                                   // 512 KB scaled bf16
    float* eip = (float*)((char*)d_ws + (size_t)NN * DD * 2);    // 16 KB exp2(-si2)
    float* ajp = eip + NN;                                       // 16 KB alpha*exp2(-sj2)

    svr_prep<<<dim3(NN * DD / 8 / 256), dim3(256), 0, stream>>>(F, alpha, bias, Ft, eip, ajp, out);
    svr_mfma8<<<dim3(NN / (4 * WPT * 16), NPY), dim3(256), 0, stream>>>((const bf16x8*)Ft, ajp, eip, out);
}

// Round 16
// 15.762 us; speedup vs baseline: 1.0993x; 1.0993x over previous
//
#include <hip/hip_runtime.h>

// SVR: out[i] = sum_j exp(-|f_i-f_j|^2/50)*alpha[j] + bias.  N=4096, D=64.
// Round 16 = exact revert to R14 (session best: 15.84us, absmax 0.0625).
// R15 (WPT=8, 1 block/CU) regressed to 17.3: at 1 wave/SIMD the dependent
// MFMA->exp->fma chain can't be covered by a co-resident wave. R12 (TLP x2)
// was null. Operating point: WPT=4 i-tiles/wave, NPY=32 j-chunks, 2 blocks/CU.
//
// Structure: prep (retile fp32->bf16*sqrt(K1) frag-order Ft, norms,
// ajp=alpha*exp2(-sj2), out=bias) + mfma4 (4 i-tiles/wave, chained MFMA,
// raw v_exp_f32, atomicAdd).
//
// Frag map (16x16x32 bf16): lane l of tile t, half h: row=16*t+(l&15),
// k=32*h+(l>>4)*8..+7 -> chunk (t*2+h)*64+l.  A/B share lane->k map.
// C/D: col=lane&15 (i), row=(lane>>4)*4+reg (j)  [verified m89; R4-R15 passed]

#define NN 4096
#define DD 64
#define NPY 32                 // j-chunks; 8 j-tiles (256 j-rows) each
#define NT (NN / 16)           // 256 row-tiles

typedef __attribute__((ext_vector_type(8))) short bf16x8;
typedef __attribute__((ext_vector_type(8))) unsigned short u16x8;
typedef __attribute__((ext_vector_type(4))) float f32x4;

#define C2 0.028853901f        // log2(e)/50
#define SQK 0.2402244f         // sqrt(2*log2(e)/50)

static __device__ __forceinline__ float fexp2(float x) {   // raw v_exp_f32 (2^x)
#if __has_builtin(__builtin_amdgcn_exp2f)
    return __builtin_amdgcn_exp2f(x);
#else
    float r;
    asm("v_exp_f32 %0, %1" : "=v"(r) : "v"(x));
    return r;
#endif
}

static __device__ __forceinline__ unsigned short f2bf(float f) {
    unsigned int x = __float_as_uint(f);
    x += 0x7fffu + ((x >> 16) & 1u);          // RNE
    return (unsigned short)(x >> 16);
}

// ---------- prep: retile+convert (scaled), norms, ajp, out=bias ----------
__global__ __launch_bounds__(256) void svr_prep(const float* __restrict__ F,
                                                const float* __restrict__ alpha,
                                                const float* __restrict__ bias,
                                                u16x8* __restrict__ Ft,
                                                float* __restrict__ sq2,
                                                float* __restrict__ ajp,
                                                float* __restrict__ out) {
    __shared__ float part[256];
    const int tid = threadIdx.x;
    const int g = blockIdx.x * 256 + tid;           // 0..32767
    const int l = g & 63;
    const int h = (g >> 6) & 1;
    const int t = g >> 7;
    const int row = t * 16 + (l & 15);
    const int k0  = h * 32 + (l >> 4) * 8;

    const float4* src = reinterpret_cast<const float4*>(F + (size_t)row * DD + k0);
    const float4 v0 = src[0];
    const float4 v1 = src[1];
    u16x8 u;                                        // scaled by sqrt(K1)
    u[0] = f2bf(v0.x * SQK); u[1] = f2bf(v0.y * SQK);
    u[2] = f2bf(v0.z * SQK); u[3] = f2bf(v0.w * SQK);
    u[4] = f2bf(v1.x * SQK); u[5] = f2bf(v1.y * SQK);
    u[6] = f2bf(v1.z * SQK); u[7] = f2bf(v1.w * SQK);
    Ft[g] = u;

    float p = v0.x * v0.x;                          // unscaled norms
    p = fmaf(v0.y, v0.y, p); p = fmaf(v0.z, v0.z, p); p = fmaf(v0.w, v0.w, p);
    p = fmaf(v1.x, v1.x, p); p = fmaf(v1.y, v1.y, p); p = fmaf(v1.z, v1.z, p);
    p = fmaf(v1.w, v1.w, p);
    part[tid] = p;
    __syncthreads();
    if ((tid & 112) == 0) {    // one thread per row: tid in {0..15, 128..143}
        float s = part[tid]      + part[tid + 16] + part[tid + 32] + part[tid + 48]
                + part[tid + 64] + part[tid + 80] + part[tid + 96] + part[tid + 112];
        const float w = s * C2;                     // si2 = |f|^2 * log2(e)/50
        sq2[row] = w;
        ajp[row] = alpha[row] * fexp2(-w);          // alpha_j * exp2(-sj2)
    }
    if (g < NN) out[g] = bias[0];                   // re-init every call
}

// ---------- main: 4 i-tiles/wave, chained MFMA, raw exp2 ----------
__global__ __launch_bounds__(256) void svr_mfma4(const bf16x8* __restrict__ Ft,
                                                 const float* __restrict__ ajp,
                                                 const float* __restrict__ sq2,
                                                 float* __restrict__ out) {
    const int lane = threadIdx.x & 63;
    const int wave = threadIdx.x >> 6;
    const int ig   = blockIdx.x * 4 + wave;          // i-group 0..63 (64 rows)
    const int it0  = ig * 4;
    const int iBase = it0 * 16;
    const int p    = blockIdx.y;                     // 0..31
    const int jt0  = p * (NT / NPY);                 // 8 j-tiles
    const int kg   = lane >> 4;
    const int c    = lane & 15;

    // B-frags for 4 i-tiles (32 VGPR, resident) + i-side exp scales
    const bf16x8 b00 = Ft[(it0 + 0) * 128 + lane], b01 = Ft[(it0 + 0) * 128 + 64 + lane];
    const bf16x8 b10 = Ft[(it0 + 1) * 128 + lane], b11 = Ft[(it0 + 1) * 128 + 64 + lane];
    const bf16x8 b20 = Ft[(it0 + 2) * 128 + lane], b21 = Ft[(it0 + 2) * 128 + 64 + lane];
    const bf16x8 b30 = Ft[(it0 + 3) * 128 + lane], b31 = Ft[(it0 + 3) * 128 + 64 + lane];
    const float e0 = fexp2(-sq2[iBase + c]);
    const float e1 = fexp2(-sq2[iBase + 16 + c]);
    const float e2 = fexp2(-sq2[iBase + 32 + c]);
    const float e3 = fexp2(-sq2[iBase + 48 + c]);

    const float4* alv = reinterpret_cast<const float4*>(ajp);

    f32x4 acc0 = {0.f,0.f,0.f,0.f}, acc1 = {0.f,0.f,0.f,0.f};
    f32x4 acc2 = {0.f,0.f,0.f,0.f}, acc3 = {0.f,0.f,0.f,0.f};

#pragma unroll
    for (int k = 0; k < NT / NPY; ++k) {
        const int jt = jt0 + k;
        const bf16x8 a0 = Ft[jt * 128 + lane];       // 1KB coalesced loads
        const bf16x8 a1 = Ft[jt * 128 + 64 + lane];
        const float4 aj = alv[jt * 4 + kg];
#define TILE(acc, bA, bB)                                                   \
        {                                                                   \
            f32x4 d = {0.f,0.f,0.f,0.f};                                    \
            d = __builtin_amdgcn_mfma_f32_16x16x32_bf16(a0, bA, d, 0,0,0);  \
            d = __builtin_amdgcn_mfma_f32_16x16x32_bf16(a1, bB, d, 0,0,0);  \
            acc.x = fmaf(fexp2(d[0]), aj.x, acc.x);                         \
            acc.y = fmaf(fexp2(d[1]), aj.y, acc.y);                         \
            acc.z = fmaf(fexp2(d[2]), aj.z, acc.z);                         \
            acc.w = fmaf(fexp2(d[3]), aj.w, acc.w);                         \
        }
        TILE(acc0, b00, b01)
        TILE(acc1, b10, b11)
        TILE(acc2, b20, b21)
        TILE(acc3, b30, b31)
#undef TILE
    }

    float s0 = (acc0.x + acc0.y) + (acc0.z + acc0.w);
    float s1 = (acc1.x + acc1.y) + (acc1.z + acc1.w);
    float s2 = (acc2.x + acc2.y) + (acc2.z + acc2.w);
    float s3 = (acc3.x + acc3.y) + (acc3.z + acc3.w);
    s0 += __shfl_xor(s0, 16); s0 += __shfl_xor(s0, 32);
    s1 += __shfl_xor(s1, 16); s1 += __shfl_xor(s1, 32);
    s2 += __shfl_xor(s2, 16); s2 += __shfl_xor(s2, 32);
    s3 += __shfl_xor(s3, 16); s3 += __shfl_xor(s3, 32);
    if (lane < 16) {                                 // apply exp2(-si2) once
        atomicAdd(&out[iBase      + lane], s0 * e0);
        atomicAdd(&out[iBase + 16 + lane], s1 * e1);
        atomicAdd(&out[iBase + 32 + lane], s2 * e2);
        atomicAdd(&out[iBase + 48 + lane], s3 * e3);
    }
}

// ---------------- launch ----------------
extern "C" void kernel_launch(void* const* d_in, const int* in_sizes, int n_in,
                              void* d_out, int out_size, void* d_ws, size_t ws_size,
                              hipStream_t stream) {
    const float* F     = (const float*)d_in[0];
    const float* alpha = (const float*)d_in[1];
    const float* bias  = (const float*)d_in[2];
    float* out = (float*)d_out;

    u16x8* Ft  = (u16x8*)d_ws;                                   // 512 KB scaled bf16
    float* sq2 = (float*)((char*)d_ws + (size_t)NN * DD * 2);    // 16 KB si2
    float* ajp = sq2 + NN;                                       // 16 KB alpha*exp2(-sj2)

    svr_prep<<<dim3(NN * DD / 8 / 256), dim3(256), 0, stream>>>(F, alpha, bias, Ft, sq2, ajp, out);
    svr_mfma4<<<dim3(16, NPY), dim3(256), 0, stream>>>((const bf16x8*)Ft, ajp, sq2, out);
}